// Round 1
// 115.516 us; speedup vs baseline: 1.0719x; 1.0719x over previous
//
#include <hip/hip_runtime.h>
#include <math.h>

// Problem constants (fixed by the reference).
#define BB 8
#define LL 12
#define TT 36
#define DD 1024
#define CC 32

// ---------------------------------------------------------------------------
// K1: Z[t,f,g] = sum_d xh[t,d,f]*xl[d,g] (9) and H[t,f] = sum_d xh[t,d,f] (3)
// per (bl,t). One wave per block, 3456 blocks; lane owns 16 d as FOUR 4-d
// chunks at stride 256 (d = 4*lane + 256*j + 0..3). Loads are
// a4[j*3+i] = xh4[3*lane + 192*j + i]: 48 B lane stride, and each contiguous
// 3 KB span is fully covered by 3 ADJACENT instructions -> L1 line reuse
// needs only ~3 KB resident (old 192 B-stride layout needed the whole 12 KB
// wave footprint across a 12-instruction window; with 12 waves/CU that
// thrashed L1/L2 and amplified HBM fetch ~4x). Same 24 float4 loads in
// flight, same 12-value shuffle reduction, lane 0 stores 48 B.
// t==0 blocks additionally emit XLs[bl][g] = sum_d xl[d,g].
// ---------------------------------------------------------------------------
__global__ __launch_bounds__(64) void k_Z(const float* __restrict__ xl,
                                          const float* __restrict__ xh,
                                          float* __restrict__ Zg,
                                          float* __restrict__ XLg) {
  const int blk  = blockIdx.x;          // bl*TT + t
  const int bl   = blk / TT;
  const int lane = threadIdx.x;         // 0..63
  const float4* xh4 = (const float4*)xh + (size_t)blk * 768;
  const float4* xl4 = (const float4*)xl + (size_t)bl  * 768;

  float4 a4[12], b4[12];                // 24 loads in flight together
  #pragma unroll
  for (int j = 0; j < 4; ++j)
    #pragma unroll
    for (int i = 0; i < 3; ++i)
      a4[j*3+i] = xh4[3*lane + 192*j + i];
  #pragma unroll
  for (int j = 0; j < 4; ++j)
    #pragma unroll
    for (int i = 0; i < 3; ++i)
      b4[j*3+i] = xl4[3*lane + 192*j + i];

  float Z00=0,Z01=0,Z02=0,Z10=0,Z11=0,Z12=0,Z20=0,Z21=0,Z22=0;
  float H0=0,H1=0,H2=0;
  const float* a = (const float*)a4;
  const float* b = (const float*)b4;
  #pragma unroll
  for (int k = 0; k < 16; ++k) {        // 16 d per lane (4 per j), xh/xl matched
    const float x0=a[k*3], x1=a[k*3+1], x2=a[k*3+2];
    const float y0=b[k*3], y1=b[k*3+1], y2=b[k*3+2];
    Z00 = fmaf(x0,y0,Z00); Z01 = fmaf(x0,y1,Z01); Z02 = fmaf(x0,y2,Z02);
    Z10 = fmaf(x1,y0,Z10); Z11 = fmaf(x1,y1,Z11); Z12 = fmaf(x1,y2,Z12);
    Z20 = fmaf(x2,y0,Z20); Z21 = fmaf(x2,y1,Z21); Z22 = fmaf(x2,y2,Z22);
    H0 += x0; H1 += x1; H2 += x2;
  }

  float v[12] = {Z00,Z01,Z02,Z10,Z11,Z12,Z20,Z21,Z22,H0,H1,H2};
  #pragma unroll
  for (int off = 32; off > 0; off >>= 1)
    #pragma unroll
    for (int j = 0; j < 12; ++j) v[j] += __shfl_down(v[j], off);

  if (lane == 0) {
    float4* o = (float4*)(Zg + (size_t)blk * 16);
    o[0] = make_float4(v[0], v[1], v[2],  v[3]);
    o[1] = make_float4(v[4], v[5], v[6],  v[7]);
    o[2] = make_float4(v[8], v[9], v[10], v[11]);
  }

  if (blk == bl * TT) {                 // t == 0: also reduce xl -> XLs
    float s0=0.f, s1=0.f, s2=0.f;
    #pragma unroll
    for (int k = 0; k < 16; ++k) {
      s0 += b[k*3]; s1 += b[k*3+1]; s2 += b[k*3+2];
    }
    #pragma unroll
    for (int off = 32; off > 0; off >>= 1) {
      s0 += __shfl_down(s0, off);
      s1 += __shfl_down(s1, off);
      s2 += __shfl_down(s2, off);
    }
    if (lane == 0) {
      XLg[bl*4+0] = s0; XLg[bl*4+1] = s1; XLg[bl*4+2] = s2;
    }
  }
}

// ---------------------------------------------------------------------------
// K2 (merged): per-block softmax prologue from Zg (tiny, redundant 8x per bl)
// then o[c,d] = sum_t sum_f att[t,c]*Wc[c,f]*xh[t,d,f]; out = o + bc + q.
// grid (96, 8) = 768 blocks = EXACTLY 3 blocks/CU. 256 thr = (g = tid&31:
// 4-d group of the 128-d slice) x (h5 = tid>>5: 4 channels). Half-wave
// coalesced xh loads (512B/instr), ring-6 register prefetch (ring-3 only
// covered ~450 cy of queue-inflated HBM latency -> per-iter stalls; 6 deep
// covers ~1800 cy), P in LDS as [t][f][c4] float4 (2 distinct addrs/wave =
// free broadcast). acc[4][4] = 16 regs; residual xl load hoisted above the
// t-loop so its latency hides under the MACs. __launch_bounds__(256,3) pins
// VGPR <= ~170 so the grid's 3 blocks/CU (12 waves) stay resident.
// ---------------------------------------------------------------------------
__global__ __launch_bounds__(256, 3) void k_out(const float* __restrict__ xl,
                                                const float* __restrict__ xh,
                                                const float* __restrict__ Zg,
                                                const float* __restrict__ XLg,
                                                const float* __restrict__ Wm,
                                                const float* __restrict__ bm,
                                                const float* __restrict__ Wq,
                                                const float* __restrict__ bq,
                                                const float* __restrict__ Wc,
                                                const float* __restrict__ bc,
                                                float* __restrict__ out) {
  __shared__ __align__(16) float ZS[TT * 16];     // 2.3 KB
  __shared__ float S[TT][CC];                     // 4.6 KB
  __shared__ __align__(16) float PS[TT * 3 * CC]; // 13.8 KB
  __shared__ float mxv[CC], inv[CC];
  const int bl = blockIdx.x;
  const int b = bl / LL, l = bl % LL;
  const int dh = blockIdx.y;            // 0..7 (128-d slice)
  const int tid = threadIdx.x;
  const int c = tid & 31;               // channel for prologue loops

  if (tid < TT * 4) ((float4*)ZS)[tid] = ((const float4*)(Zg + (size_t)bl * TT * 16))[tid];
  __syncthreads();

  {                                     // S[t][c] = relu(mq[c,t]) from Z/H
    const float XL0 = XLg[bl*4+0], XL1 = XLg[bl*4+1], XL2 = XLg[bl*4+2];
    const float wm0 = Wm[c*3], wm1 = Wm[c*3+1], wm2 = Wm[c*3+2];
    const float wq0 = Wq[c*3], wq1 = Wq[c*3+1], wq2 = Wq[c*3+2];
    const float bqv = bq[c], bmv = bm[c];
    const float K = bmv * (fmaf(wq0, XL0, fmaf(wq1, XL1, wq2 * XL2)) + 1024.f * bqv);
    for (int idx = tid; idx < TT * CC; idx += 256) {
      const int t = idx >> 5;           // c == tid&31 for every iteration
      const float* z = &ZS[t * 16];
      float m = K;
      m = fmaf(wm0, fmaf(wq0, z[0], fmaf(wq1, z[1], fmaf(wq2, z[2], bqv * z[9]))),  m);
      m = fmaf(wm1, fmaf(wq0, z[3], fmaf(wq1, z[4], fmaf(wq2, z[5], bqv * z[10]))), m);
      m = fmaf(wm2, fmaf(wq0, z[6], fmaf(wq1, z[7], fmaf(wq2, z[8], bqv * z[11]))), m);
      S[t][c] = fmaxf(m, 0.f);
    }
  }
  __syncthreads();

  if (tid < CC) {
    float mx = 0.f;                     // relu >= 0 -> valid seed
    #pragma unroll
    for (int t = 0; t < TT; ++t) mx = fmaxf(mx, S[t][tid]);
    float ssum = 0.f;
    #pragma unroll
    for (int t = 0; t < TT; ++t) ssum += __expf(S[t][tid] - mx);
    mxv[tid] = mx;
    inv[tid] = 1.f / ssum;
  }
  __syncthreads();

  {                                     // P[t][f][c] = att * Wc[c][f]
    const float wc0 = Wc[c*3], wc1 = Wc[c*3+1], wc2 = Wc[c*3+2];
    const float mxc = mxv[c], invc = inv[c];
    for (int idx = tid; idx < TT * CC; idx += 256) {
      const int t = idx >> 5;
      const float e = __expf(S[t][c] - mxc) * invc;
      PS[(t*3+0)*CC + c] = e * wc0;
      PS[(t*3+1)*CC + c] = e * wc1;
      PS[(t*3+2)*CC + c] = e * wc2;
    }
  }
  __syncthreads();

  const int g  = tid & 31;              // 4-d group within the 128-d slice
  const int h5 = tid >> 5;              // 0..7 -> 4 channels
  const int c0 = h5 * 4;
  const int dg = dh * 32 + g;           // global 4-d group (0..255)

  const float4* base = (const float4*)xh + (size_t)bl * TT * 768 + dg * 3;
  float4 buf[6][3];                     // ring-6 prefetch
  #pragma unroll
  for (int j = 0; j < 6; ++j)
    #pragma unroll
    for (int i = 0; i < 3; ++i) buf[j][i] = base[(size_t)j * 768 + i];

  // Residual q inputs: issue now, consumed in the epilogue (latency hidden).
  float4 ql[3];
  {
    const float4* xl4 = (const float4*)xl + (size_t)bl * 768 + dg * 3;
    #pragma unroll
    for (int i = 0; i < 3; ++i) ql[i] = xl4[i];
  }

  float acc[4][4];
  #pragma unroll
  for (int u = 0; u < 4; ++u)
    #pragma unroll
    for (int dd = 0; dd < 4; ++dd) acc[u][dd] = 0.f;

  const float4* PS4 = (const float4*)PS;
  #pragma unroll
  for (int t = 0; t < TT; ++t) {
    const int sl = t % 6;               // compile-time under full unroll
    float xv[12];
    {
      const float* x = (const float*)buf[sl];
      #pragma unroll
      for (int i = 0; i < 12; ++i) xv[i] = x[i];
    }
    if (t + 6 < TT) {                   // ring prefetch, 6 t ahead
      const float4* p = base + (size_t)(t + 6) * 768;
      #pragma unroll
      for (int i = 0; i < 3; ++i) buf[sl][i] = p[i];
    }
    const float4 P0 = PS4[(t*3+0)*8 + h5];   // 2 addrs/wave: free broadcast
    const float4 P1 = PS4[(t*3+1)*8 + h5];
    const float4 P2 = PS4[(t*3+2)*8 + h5];
    const float p0[4] = {P0.x, P0.y, P0.z, P0.w};
    const float p1[4] = {P1.x, P1.y, P1.z, P1.w};
    const float p2[4] = {P2.x, P2.y, P2.z, P2.w};
    #pragma unroll
    for (int u = 0; u < 4; ++u)
      #pragma unroll
      for (int dd = 0; dd < 4; ++dd)
        acc[u][dd] = fmaf(p0[u], xv[dd*3],
                     fmaf(p1[u], xv[dd*3+1],
                     fmaf(p2[u], xv[dd*3+2], acc[u][dd])));
  }

  // Epilogue: + bc (sum att = 1) + residual q; float4 stores.
  const float* y = (const float*)ql;    // 12 floats = 4 d x 3 f
  #pragma unroll
  for (int u = 0; u < 4; ++u) {
    const int cc = c0 + u;
    const float w0 = Wq[cc*3], w1 = Wq[cc*3+1], w2 = Wq[cc*3+2];
    const float b0 = bq[cc], bcv = bc[cc];
    float4 o;
    o.x = acc[u][0] + bcv + fmaf(w0, y[0], fmaf(w1, y[1],  fmaf(w2, y[2],  b0)));
    o.y = acc[u][1] + bcv + fmaf(w0, y[3], fmaf(w1, y[4],  fmaf(w2, y[5],  b0)));
    o.z = acc[u][2] + bcv + fmaf(w0, y[6], fmaf(w1, y[7],  fmaf(w2, y[8],  b0)));
    o.w = acc[u][3] + bcv + fmaf(w0, y[9], fmaf(w1, y[10], fmaf(w2, y[11], b0)));
    *(float4*)(out + (((size_t)b * CC + cc) * LL + l) * DD + dg * 4) = o;
  }
}

// ---------------------------------------------------------------------------
extern "C" void kernel_launch(void* const* d_in, const int* in_sizes, int n_in,
                              void* d_out, int out_size, void* d_ws, size_t ws_size,
                              hipStream_t stream) {
  const float* xl = (const float*)d_in[0];  // (B,L,D,F)
  const float* xh = (const float*)d_in[1];  // (B,L,T,D,F)
  const float* Wq = (const float*)d_in[2];
  const float* bq = (const float*)d_in[3];
  const float* Wm = (const float*)d_in[4];
  const float* bm = (const float*)d_in[5];
  const float* Wc = (const float*)d_in[6];
  const float* bc = (const float*)d_in[7];
  float* out = (float*)d_out;               // (B,C,L,D)

  float* Zg  = (float*)d_ws;                        // [bl*T][16], 221 KB
  float* XLg = Zg + (size_t)BB * LL * TT * 16;      // [bl][4], 1.5 KB

  k_Z  <<<dim3(BB * LL * TT), 64,  0, stream>>>(xl, xh, Zg, XLg);
  k_out<<<dim3(BB * LL, 8),   256, 0, stream>>>(xl, xh, Zg, XLg, Wm, bm, Wq, bq,
                                                Wc, bc, out);
}